// Round 1
// baseline (314.487 us; speedup 1.0000x reference)
//
#include <hip/hip_runtime.h>

typedef __attribute__((ext_vector_type(8))) short bf16x8;
typedef __attribute__((ext_vector_type(4))) float f32x4;

__device__ __forceinline__ unsigned short f2bf(float f) {
    union { float f; unsigned int u; } v; v.f = f;
    unsigned int u = v.u;
    return (unsigned short)((u + 0x7FFFu + ((u >> 16) & 1u)) >> 16);
}

// ---------------- leaf level (j=9): emb9 = relu(contents_9 @ Wu^T + bu) ----------------
__global__ __launch_bounds__(256) void k_leaf(const float* __restrict__ contents,
                                              const float* __restrict__ Wu,
                                              const float* __restrict__ bu,
                                              unsigned short* __restrict__ emb,
                                              int nrows) {
    __shared__ float c_s[16][8];
    int t = threadIdx.x;
    int lr = t >> 4, nc = t & 15;
    // per-thread W rows n = nc*8+o in registers (4KB total, L1/L2-hot)
    float Wr[8][8], bs[8];
    #pragma unroll
    for (int o = 0; o < 8; ++o) {
        int n = nc * 8 + o;
        #pragma unroll
        for (int k = 0; k < 8; ++k) Wr[o][k] = Wu[n * 8 + k];
        bs[o] = bu[n];
    }
    int ngroups = nrows >> 4;
    for (int rb = blockIdx.x; rb < ngroups; rb += gridDim.x) {
        int row0 = rb * 16;
        __syncthreads();
        if (t < 128) c_s[t >> 3][t & 7] = contents[row0 * 8 + t];
        __syncthreads();
        float c[8];
        #pragma unroll
        for (int k = 0; k < 8; ++k) c[k] = c_s[lr][k];
        bf16x8 pack;
        #pragma unroll
        for (int o = 0; o < 8; ++o) {
            float s = bs[o];
            #pragma unroll
            for (int k = 0; k < 8; ++k) s += c[k] * Wr[o][k];
            ((unsigned short*)&pack)[o] = f2bf(fmaxf(s, 0.f));
        }
        *reinterpret_cast<bf16x8*>(emb + (size_t)(row0 + lr) * 128 + nc * 8) = pack;
    }
}

// ---------------- level kernel (j<=8) ----------------
// emb_j[i] = relu( sum_c emb_{j+1}[2i+c] @ Wh_c^T + relu(c_j[i]@Wu^T+bu) @ Whu^T + bh )
template<int IS_LAST>
__global__ __launch_bounds__(256) void k_level(
    const unsigned short* __restrict__ embIn,  // [2n][128] bf16
    const float* __restrict__ contents,        // [n][8] f32
    const float* __restrict__ Wh,              // [128][384] f32
    const float* __restrict__ Wu,              // [128][8] f32
    const float* __restrict__ bu,              // [128]
    const float* __restrict__ bh,              // [128]
    unsigned short* __restrict__ embOut,       // [n][128] bf16
    float* __restrict__ outF,                  // [n][128] f32 (last level)
    int n_nodes)
{
    // LDS: 32K + 16K + 4K + 96K + 8K + 0.5K = 156.5 KiB (1 block/CU)
    __shared__ __align__(16) unsigned short A_lds[2][64][128]; // [child c][node][k], XOR-swz
    __shared__ __align__(16) unsigned short u_lds[64][128];    // u tile, XOR-swz
    __shared__ __align__(16) unsigned short cpad[64][32];      // contents padded, col8=1.0
    __shared__ __align__(16) unsigned short W_lds[128][384];   // Wh bf16, XOR-swz
    __shared__ __align__(16) unsigned short Wu_pad[128][32];   // Wu padded, col8=bu
    __shared__ float bh_lds[128];

    int t = threadIdx.x;
    // ---- one-time staging ----
    for (int e = t; e < 64 * 32; e += 256) ((unsigned short*)cpad)[e] = 0;
    for (int e = t; e < 128 * 32; e += 256) ((unsigned short*)Wu_pad)[e] = 0;
    __syncthreads();
    for (int e = t; e < 128 * 384; e += 256) {
        int n = e / 384, k = e % 384;
        W_lds[n][((k >> 3) ^ (n & 7)) * 8 + (k & 7)] = f2bf(Wh[e]);
    }
    for (int e = t; e < 128 * 8; e += 256) {
        int n = e >> 3, k = e & 7;
        Wu_pad[n][k ^ ((n & 3) << 3)] = f2bf(Wu[e]);
    }
    if (t < 128) {
        Wu_pad[t][8 ^ ((t & 3) << 3)] = f2bf(bu[t]);
        bh_lds[t] = bh[t];
    }
    if (t < 64) cpad[t][8 ^ ((t & 3) << 3)] = 0x3F80; // 1.0 in bf16 (bu fold)

    int lane = t & 63, wid = t >> 6;
    int wr = wid >> 1, wc = wid & 1;       // wave tile: rows wr*32..+32, cols wc*64..+64
    int l15 = lane & 15, l4 = lane >> 4;
    int ntiles = n_nodes >> 6;

    for (int tile = blockIdx.x; tile < ntiles; tile += gridDim.x) {
        __syncthreads();
        // ---- stage A: 128 contiguous child rows, de-interleave even/odd ----
        const bf16x8* src = reinterpret_cast<const bf16x8*>(embIn + (size_t)tile * 128 * 128);
        #pragma unroll
        for (int it = 0; it < 8; ++it) {
            int q = t + it * 256;           // 16B chunk id, 2048 total
            int r = q >> 4, ks = q & 15;    // source row, 16B slot in row
            int c = r & 1, i = r >> 1;
            bf16x8 v = src[q];
            *reinterpret_cast<bf16x8*>(&A_lds[c][i][(ks ^ (i & 7)) * 8]) = v;
        }
        // ---- stage contents values (k<8 slots only; zeros/1.0 persist) ----
        {
            const float* cs = contents + (size_t)tile * 64 * 8;
            #pragma unroll
            for (int it = 0; it < 2; ++it) {
                int e = t + it * 256;
                int i = e >> 3, k = e & 7;
                cpad[i][k ^ ((i & 3) << 3)] = f2bf(cs[e]);
            }
        }
        __syncthreads();

        // ---- u-step: u = relu(cpad @ Wu_pad^T) via one K=32 MFMA per frag ----
        {
            bf16x8 au[2], buf[4];
            #pragma unroll
            for (int mf = 0; mf < 2; ++mf) {
                int i = wr * 32 + mf * 16 + l15;
                au[mf] = *reinterpret_cast<const bf16x8*>(&cpad[i][(l4 ^ (i & 3)) * 8]);
            }
            #pragma unroll
            for (int nf = 0; nf < 4; ++nf) {
                int n = wc * 64 + nf * 16 + l15;
                buf[nf] = *reinterpret_cast<const bf16x8*>(&Wu_pad[n][(l4 ^ (n & 3)) * 8]);
            }
            #pragma unroll
            for (int mf = 0; mf < 2; ++mf)
                #pragma unroll
                for (int nf = 0; nf < 4; ++nf) {
                    f32x4 z = {0.f, 0.f, 0.f, 0.f};
                    z = __builtin_amdgcn_mfma_f32_16x16x32_bf16(au[mf], buf[nf], z, 0, 0, 0);
                    #pragma unroll
                    for (int r = 0; r < 4; ++r) {
                        int iu = wr * 32 + mf * 16 + l4 * 4 + r;
                        int nn = wc * 64 + nf * 16 + l15;
                        u_lds[iu][nn ^ ((iu & 7) << 3)] = f2bf(fmaxf(z[r], 0.f));
                    }
                }
        }
        __syncthreads();

        // ---- main GEMM: K = 384 (A even / A odd / u), acc init with bh ----
        f32x4 acc[2][4];
        #pragma unroll
        for (int nf = 0; nf < 4; ++nf) {
            float bv = bh_lds[wc * 64 + nf * 16 + l15];
            #pragma unroll
            for (int mf = 0; mf < 2; ++mf) acc[mf][nf] = (f32x4){bv, bv, bv, bv};
        }
        #pragma unroll
        for (int kb = 0; kb < 12; ++kb) {
            bf16x8 af[2], bfr[4];
            #pragma unroll
            for (int mf = 0; mf < 2; ++mf) {
                int i = wr * 32 + mf * 16 + l15;
                const unsigned short* ap;
                if (kb < 8) ap = &A_lds[kb >> 2][i][((((kb & 3) * 4) + l4) ^ (i & 7)) * 8];
                else        ap = &u_lds[i][((((kb - 8) * 4) + l4) ^ (i & 7)) * 8];
                af[mf] = *reinterpret_cast<const bf16x8*>(ap);
            }
            #pragma unroll
            for (int nf = 0; nf < 4; ++nf) {
                int n = wc * 64 + nf * 16 + l15;
                bfr[nf] = *reinterpret_cast<const bf16x8*>(&W_lds[n][((kb * 4 + l4) ^ (n & 7)) * 8]);
            }
            #pragma unroll
            for (int mf = 0; mf < 2; ++mf)
                #pragma unroll
                for (int nf = 0; nf < 4; ++nf)
                    acc[mf][nf] = __builtin_amdgcn_mfma_f32_16x16x32_bf16(af[mf], bfr[nf], acc[mf][nf], 0, 0, 0);
        }
        // ---- epilogue: relu + store ----
        #pragma unroll
        for (int mf = 0; mf < 2; ++mf)
            #pragma unroll
            for (int nf = 0; nf < 4; ++nf)
                #pragma unroll
                for (int r = 0; r < 4; ++r) {
                    int i = wr * 32 + mf * 16 + l4 * 4 + r;
                    int n = wc * 64 + nf * 16 + l15;
                    float v = fmaxf(acc[mf][nf][r], 0.f);
                    size_t idx = (size_t)(tile * 64 + i) * 128 + n;
                    if (IS_LAST) outF[idx] = v;
                    else         embOut[idx] = f2bf(v);
                }
    }
}

extern "C" void kernel_launch(void* const* d_in, const int* in_sizes, int n_in,
                              void* d_out, int out_size, void* d_ws, size_t ws_size,
                              hipStream_t stream) {
    const float* contents[10];
    for (int j = 0; j < 10; ++j) contents[j] = (const float*)d_in[j];
    const float* Wu = (const float*)d_in[19];
    const float* bu = (const float*)d_in[20];
    const float* Wh = (const float*)d_in[21];
    const float* bh = (const float*)d_in[22];

    // ws ping-pong: bufA holds odd-level embs (max: emb9 = 128 MiB), bufB even (max: emb8 = 64 MiB)
    unsigned short* bufA = (unsigned short*)d_ws;
    unsigned short* bufB = (unsigned short*)((char*)d_ws + (size_t)134217728);

    // level 9 (leaf): 524288 rows
    k_leaf<<<4096, 256, 0, stream>>>(contents[9], Wu, bu, bufA, 1024 << 9);

    // levels 8..1
    for (int j = 8; j >= 1; --j) {
        int n = 1024 << j;
        const unsigned short* in = (j & 1) ? bufB : bufA; // emb_{j+1}: (j+1) odd -> A
        unsigned short* outp = (j & 1) ? bufA : bufB;     // emb_j:     j odd    -> A
        int grid = n / 64; if (grid > 256) grid = 256;
        k_level<0><<<grid, 256, 0, stream>>>(in, contents[j], Wh, Wu, bu, bh, outp, nullptr, n);
    }
    // level 0 -> f32 output
    k_level<1><<<16, 256, 0, stream>>>(bufA, contents[0], Wh, Wu, bu, bh, nullptr, (float*)d_out, 1024);
}